// Round 1
// baseline (740.275 us; speedup 1.0000x reference)
//
#include <hip/hip_runtime.h>

// Problem constants
#define Tn 512
#define Sn 512
#define Bn 8
#define Dn 512
#define Hn 8
#define HDn 64
#define Ln 8
#define Fn 2048
#define SCALE 0.125f

typedef short short8 __attribute__((ext_vector_type(8)));
typedef float floatx4 __attribute__((ext_vector_type(4)));

__device__ __forceinline__ unsigned short f2b(float f) {
    unsigned int u = __float_as_uint(f);
    u += 0x7FFFu + ((u >> 16) & 1u);   // round-to-nearest-even
    return (unsigned short)(u >> 16);
}

// ---------------------------------------------------------------------------
// Prep: (T,B,D) f32 -> (B*T, D) bf16 rows
__global__ __launch_bounds__(256) void to_rows_bf16(const float* __restrict__ in,
                                                    unsigned short* __restrict__ out, int T_) {
    size_t n = (size_t)blockIdx.x * 256 + threadIdx.x;
    size_t total = (size_t)T_ * Bn * Dn;
    if (n >= total) return;
    int d = (int)(n & (Dn - 1));
    size_t rt = n >> 9;              // Dn = 512
    int t = (int)(rt % T_);
    int b = (int)(rt / T_);
    out[n] = f2b(in[((size_t)t * Bn + b) * Dn + d]);
}

__global__ __launch_bounds__(256) void conv_bf16(const float* __restrict__ in,
                                                 unsigned short* __restrict__ out, int n) {
    int i = blockIdx.x * 256 + threadIdx.x;
    if (i < n) out[i] = f2b(in[i]);
}

// ---------------------------------------------------------------------------
// Generic batched bf16 MFMA GEMM:  C = act(alpha * A @ W^T + bias)
// A: (M,K) bf16 lda ; W: (N,K) bf16 ldw.  Batch z -> z1=z/zdiv, z2=z%zdiv.
// mode 0: f32 row-major  1: bf16 row-major  2: bf16 heads (B,H,T,HD)  3: bf16 headsT (B,H,HD,T)
__global__ __launch_bounds__(256) void gemm_bf16(
    const unsigned short* __restrict__ A, const unsigned short* __restrict__ W,
    const float* __restrict__ bias, void* __restrict__ Cv,
    int M, int N, int K, int lda, int ldw, int ldc,
    long sA1, long sA2, long sW1, long sW2, long sC1, long sC2, int zdiv,
    float alpha, int mode, int relu, int Tp) {
    int z = blockIdx.z;
    int z1 = z / zdiv, z2 = z - z1 * zdiv;
    const unsigned short* Ab = A + (size_t)z1 * sA1 + (size_t)z2 * sA2;
    const unsigned short* Wb = W + (size_t)z1 * sW1 + (size_t)z2 * sW2;
    size_t coff = (size_t)z1 * sC1 + (size_t)z2 * sC2;
    int tid = threadIdx.x;
    int lane = tid & 63, wave = tid >> 6;
    int wm = wave & 1, wn = wave >> 1;
    int l16 = lane & 15, quad = lane >> 4;
    int m0 = blockIdx.y * 64 + wm * 32;
    int n0 = blockIdx.x * 64 + wn * 32;

    floatx4 acc00 = {0,0,0,0}, acc01 = {0,0,0,0}, acc10 = {0,0,0,0}, acc11 = {0,0,0,0};
    const unsigned short* a0p = Ab + (size_t)(m0 + l16) * lda + quad * 8;
    const unsigned short* a1p = a0p + (size_t)16 * lda;
    const unsigned short* b0p = Wb + (size_t)(n0 + l16) * ldw + quad * 8;
    const unsigned short* b1p = b0p + (size_t)16 * ldw;

    for (int kk = 0; kk < K; kk += 32) {
        short8 a0 = *(const short8*)(a0p + kk);
        short8 a1 = *(const short8*)(a1p + kk);
        short8 b0 = *(const short8*)(b0p + kk);
        short8 b1 = *(const short8*)(b1p + kk);
        acc00 = __builtin_amdgcn_mfma_f32_16x16x32_bf16(a0, b0, acc00, 0, 0, 0);
        acc01 = __builtin_amdgcn_mfma_f32_16x16x32_bf16(a0, b1, acc01, 0, 0, 0);
        acc10 = __builtin_amdgcn_mfma_f32_16x16x32_bf16(a1, b0, acc10, 0, 0, 0);
        acc11 = __builtin_amdgcn_mfma_f32_16x16x32_bf16(a1, b1, acc11, 0, 0, 0);
    }
    floatx4 accs[2][2] = {{acc00, acc01}, {acc10, acc11}};
    for (int mt = 0; mt < 2; ++mt)
        for (int nt = 0; nt < 2; ++nt) {
            int gn = n0 + nt * 16 + l16;
            float bb = bias ? bias[gn] : 0.0f;
            floatx4 v = accs[mt][nt];
            for (int r = 0; r < 4; ++r) {
                int gm = m0 + mt * 16 + quad * 4 + r;
                float val = v[r] * alpha + bb;
                if (relu) val = fmaxf(val, 0.0f);
                if (mode == 0) {
                    ((float*)Cv)[coff + (size_t)gm * ldc + gn] = val;
                } else if (mode == 1) {
                    ((unsigned short*)Cv)[coff + (size_t)gm * ldc + gn] = f2b(val);
                } else if (mode == 2) {
                    int bq = gm / Tp, t = gm - bq * Tp;
                    ((unsigned short*)Cv)[(((size_t)(bq * Hn + (gn >> 6)) * Tp + t) << 6) + (gn & 63)] = f2b(val);
                } else {
                    int bq = gm / Tp, t = gm - bq * Tp;
                    ((unsigned short*)Cv)[((size_t)(bq * Hn + (gn >> 6)) * 64 + (gn & 63)) * Tp + t] = f2b(val);
                }
            }
        }
}

// ---------------------------------------------------------------------------
// Relational scores: scores[b,h,i,j] = scale * sum_l em[b,l,i,j] * (uR_l[i,:] . k[j,:])
// Block = (j-block 64, i-block 64, b); loops h so edge_mask is L2-resident across heads.
__global__ __launch_bounds__(256) void relscores(
    const unsigned short* __restrict__ uR, const unsigned short* __restrict__ kB,
    const float* __restrict__ em, const unsigned char* __restrict__ pad,
    float* __restrict__ scores) {
    int jb = blockIdx.x, ib = blockIdx.y, b = blockIdx.z;
    int tid = threadIdx.x, lane = tid & 63, wave = tid >> 6;
    int wm = wave & 1, wn = wave >> 1;
    int l16 = lane & 15, quad = lane >> 4;
    int i0 = ib * 64 + wm * 32, j0 = jb * 64 + wn * 32;
    const unsigned char* padb = pad + (size_t)b * Tn * Tn;

    for (int h = 0; h < Hn; ++h) {
        const unsigned short* kbase = kB + (size_t)(b * Hn + h) * Tn * HDn;
        float sacc[2][2][4] = {};
        for (int l = 0; l < Ln; ++l) {
            const unsigned short* ubase = uR + ((size_t)(b * Hn + h) * Ln + l) * Tn * HDn;
            floatx4 g00 = {0,0,0,0}, g01 = {0,0,0,0}, g10 = {0,0,0,0}, g11 = {0,0,0,0};
            for (int kk = 0; kk < HDn; kk += 32) {
                short8 a0 = *(const short8*)(ubase + (size_t)(i0 + l16) * HDn + kk + quad * 8);
                short8 a1 = *(const short8*)(ubase + (size_t)(i0 + 16 + l16) * HDn + kk + quad * 8);
                short8 b0 = *(const short8*)(kbase + (size_t)(j0 + l16) * HDn + kk + quad * 8);
                short8 b1 = *(const short8*)(kbase + (size_t)(j0 + 16 + l16) * HDn + kk + quad * 8);
                g00 = __builtin_amdgcn_mfma_f32_16x16x32_bf16(a0, b0, g00, 0, 0, 0);
                g01 = __builtin_amdgcn_mfma_f32_16x16x32_bf16(a0, b1, g01, 0, 0, 0);
                g10 = __builtin_amdgcn_mfma_f32_16x16x32_bf16(a1, b0, g10, 0, 0, 0);
                g11 = __builtin_amdgcn_mfma_f32_16x16x32_bf16(a1, b1, g11, 0, 0, 0);
            }
            floatx4 gs[2][2] = {{g00, g01}, {g10, g11}};
            const float* emb = em + ((size_t)b * Ln + l) * Tn * Tn;
            for (int mt = 0; mt < 2; ++mt)
                for (int nt = 0; nt < 2; ++nt)
                    for (int r = 0; r < 4; ++r) {
                        int i = i0 + mt * 16 + quad * 4 + r;
                        int j = j0 + nt * 16 + l16;
                        sacc[mt][nt][r] += emb[(size_t)i * Tn + j] * gs[mt][nt][r];
                    }
        }
        float* sb = scores + (size_t)(b * Hn + h) * Tn * Tn;
        for (int mt = 0; mt < 2; ++mt)
            for (int nt = 0; nt < 2; ++nt)
                for (int r = 0; r < 4; ++r) {
                    int i = i0 + mt * 16 + quad * 4 + r;
                    int j = j0 + nt * 16 + l16;
                    float val = sacc[mt][nt][r] * SCALE;
                    if (padb[(size_t)i * Tn + j]) val = -1.0e9f;
                    sb[(size_t)i * Tn + j] = val;
                }
    }
}

// ---------------------------------------------------------------------------
// Row softmax (len elems f32) -> write bf16 probs in-place over the row start.
__global__ __launch_bounds__(256) void softmax_rows(float* __restrict__ buf, int rows, int len) {
    int gw = (int)(((size_t)blockIdx.x * 256 + threadIdx.x) >> 6);
    int lane = threadIdx.x & 63;
    if (gw >= rows) return;
    float* row = buf + (size_t)gw * len;
    int cc = len >> 6;               // = 8
    float vals[8];
    float mx = -3.0e38f;
    for (int c = 0; c < cc; ++c) { vals[c] = row[c * 64 + lane]; mx = fmaxf(mx, vals[c]); }
    for (int off = 32; off; off >>= 1) mx = fmaxf(mx, __shfl_xor(mx, off, 64));
    float sum = 0.f;
    for (int c = 0; c < cc; ++c) { float e = __expf(vals[c] - mx); vals[c] = e; sum += e; }
    for (int off = 32; off; off >>= 1) sum += __shfl_xor(sum, off, 64);
    float inv = 1.0f / sum;
    unsigned short* prow = (unsigned short*)row;
    for (int c = 0; c < cc; ++c) prow[c * 64 + lane] = f2b(vals[c] * inv);
}

// ---------------------------------------------------------------------------
// LayerNorm over D=512: out = (a[row] + b2[row] - mean)/sqrt(var+eps)*s + bb
__global__ __launch_bounds__(256) void ln_kernel(
    const float* __restrict__ a, int a_trans, const float* __restrict__ b2,
    const float* __restrict__ s, const float* __restrict__ bb,
    float* __restrict__ outF, int out_trans, unsigned short* __restrict__ outB) {
    int row = blockIdx.x;            // b*Tn + t
    int b = row >> 9, t = row & (Tn - 1);
    int tid = threadIdx.x;
    size_t ia = a_trans ? ((size_t)(t * Bn + b)) * Dn : (size_t)row * Dn;
    size_t ir = (size_t)row * Dn;
    float x0 = a[ia + tid];
    float x1 = a[ia + tid + 256];
    if (b2) { x0 += b2[ir + tid]; x1 += b2[ir + tid + 256]; }
    float s1 = x0 + x1, s2 = x0 * x0 + x1 * x1;
    for (int off = 32; off; off >>= 1) {
        s1 += __shfl_xor(s1, off, 64);
        s2 += __shfl_xor(s2, off, 64);
    }
    __shared__ float red[2][4];
    int wave = tid >> 6, lane = tid & 63;
    if (lane == 0) { red[0][wave] = s1; red[1][wave] = s2; }
    __syncthreads();
    float ts1 = red[0][0] + red[0][1] + red[0][2] + red[0][3];
    float ts2 = red[1][0] + red[1][1] + red[1][2] + red[1][3];
    float mean = ts1 * (1.0f / Dn);
    float var = ts2 * (1.0f / Dn) - mean * mean;
    float rs = rsqrtf(var + 1e-5f);
    float y0 = (x0 - mean) * rs * s[tid] + bb[tid];
    float y1 = (x1 - mean) * rs * s[tid + 256] + bb[tid + 256];
    size_t io = out_trans ? ((size_t)(t * Bn + b)) * Dn : ir;
    if (outF) { outF[io + tid] = y0; outF[io + tid + 256] = y1; }
    if (outB) { outB[ir + tid] = f2b(y0); outB[ir + tid + 256] = f2b(y1); }
}

// ---------------------------------------------------------------------------
extern "C" void kernel_launch(void* const* d_in, const int* in_sizes, int n_in,
                              void* d_out, int out_size, void* d_ws, size_t ws_size,
                              hipStream_t stream) {
    const float* tgt      = (const float*)d_in[0];
    const float* em       = (const float*)d_in[1];
    const unsigned char* pad = (const unsigned char*)d_in[2];
    const float* memr     = (const float*)d_in[3];
    const float* sa_q_w   = (const float*)d_in[4];
    const float* sa_q_b   = (const float*)d_in[5];
    const float* sa_k_w   = (const float*)d_in[6];
    const float* sa_k_b   = (const float*)d_in[7];
    const float* sa_v_w   = (const float*)d_in[8];
    const float* sa_v_b   = (const float*)d_in[9];
    const float* sa_rel   = (const float*)d_in[10];
    const float* sa_out_w = (const float*)d_in[11];
    const float* sa_out_b = (const float*)d_in[12];
    const float* ca_in_w  = (const float*)d_in[13];
    const float* ca_in_b  = (const float*)d_in[14];
    const float* ca_out_w = (const float*)d_in[15];
    const float* ca_out_b = (const float*)d_in[16];
    const float* lin1_w   = (const float*)d_in[17];
    const float* lin1_b   = (const float*)d_in[18];
    const float* lin2_w   = (const float*)d_in[19];
    const float* lin2_b   = (const float*)d_in[20];
    const float* ln1_s    = (const float*)d_in[21];
    const float* ln1_b    = (const float*)d_in[22];
    const float* ln2_s    = (const float*)d_in[23];
    const float* ln2_b    = (const float*)d_in[24];
    const float* ln3_s    = (const float*)d_in[25];
    const float* ln3_b    = (const float*)d_in[26];

    const size_t BT = (size_t)Bn * Tn;   // 4096

    // ---- workspace carve-out (~176 MB) ----
    char* ws = (char*)d_ws;
    size_t off = 0;
    auto alloc = [&](size_t bytes) -> char* {
        char* p = ws + off;
        off += (bytes + 255) & ~(size_t)255;
        return p;
    };
    unsigned short* xb    = (unsigned short*)alloc(BT * Dn * 2);          // x rows bf16
    unsigned short* mb    = (unsigned short*)alloc(BT * Dn * 2);          // memory rows bf16
    unsigned short* wsaq  = (unsigned short*)alloc((size_t)Dn * Dn * 2);
    unsigned short* wsak  = (unsigned short*)alloc((size_t)Dn * Dn * 2);
    unsigned short* wsav  = (unsigned short*)alloc((size_t)Dn * Dn * 2);
    unsigned short* wsao  = (unsigned short*)alloc((size_t)Dn * Dn * 2);
    unsigned short* wcain = (unsigned short*)alloc((size_t)3 * Dn * Dn * 2);
    unsigned short* wcao  = (unsigned short*)alloc((size_t)Dn * Dn * 2);
    unsigned short* wlin1 = (unsigned short*)alloc((size_t)Fn * Dn * 2);
    unsigned short* wlin2 = (unsigned short*)alloc((size_t)Dn * Fn * 2);
    unsigned short* wrel  = (unsigned short*)alloc((size_t)Ln * HDn * HDn * 2);
    unsigned short* qb    = (unsigned short*)alloc(BT * Dn * 2);          // (B,H,T,HD)
    unsigned short* kb    = (unsigned short*)alloc(BT * Dn * 2);          // (B,H,T,HD)
    unsigned short* vtb   = (unsigned short*)alloc(BT * Dn * 2);          // (B,H,HD,T)
    unsigned short* ur    = (unsigned short*)alloc((size_t)Bn * Hn * Ln * Tn * HDn * 2); // 32MB
    float*          sc    = (float*)alloc((size_t)Bn * Hn * Tn * Tn * 4); // 64MB scores / probs
    unsigned short* ob    = (unsigned short*)alloc(BT * Dn * 2);          // attn out rows bf16
    float*          t2f   = (float*)alloc(BT * Dn * 4);                   // proj output f32
    float*          x1f   = (float*)alloc(BT * Dn * 4);
    unsigned short* x1b   = (unsigned short*)alloc(BT * Dn * 2);
    float*          x2f   = (float*)alloc(BT * Dn * 4);
    unsigned short* x2b   = (unsigned short*)alloc(BT * Dn * 2);
    unsigned short* hid   = (unsigned short*)alloc(BT * Fn * 2);          // 16MB
    (void)ws_size; (void)in_sizes; (void)n_in; (void)out_size;

    auto gemm = [&](const unsigned short* A, const unsigned short* W, const float* bias,
                    void* C, int M, int N, int K, int lda, int ldw, int ldc,
                    long sA1, long sA2, long sW1, long sW2, long sC1, long sC2,
                    int zdiv, int batches, float alpha, int mode, int relu, int Tp) {
        dim3 g(N / 64, M / 64, batches);
        gemm_bf16<<<g, 256, 0, stream>>>(A, W, bias, C, M, N, K, lda, ldw, ldc,
                                         sA1, sA2, sW1, sW2, sC1, sC2, zdiv,
                                         alpha, mode, relu, Tp);
    };

    // ---- prep: transpose/convert activations, convert weights to bf16 ----
    to_rows_bf16<<<dim3((BT * Dn + 255) / 256), 256, 0, stream>>>(tgt, xb, Tn);
    to_rows_bf16<<<dim3((BT * Dn + 255) / 256), 256, 0, stream>>>(memr, mb, Sn);
    conv_bf16<<<dim3((Dn * Dn + 255) / 256), 256, 0, stream>>>(sa_q_w, wsaq, Dn * Dn);
    conv_bf16<<<dim3((Dn * Dn + 255) / 256), 256, 0, stream>>>(sa_k_w, wsak, Dn * Dn);
    conv_bf16<<<dim3((Dn * Dn + 255) / 256), 256, 0, stream>>>(sa_v_w, wsav, Dn * Dn);
    conv_bf16<<<dim3((Dn * Dn + 255) / 256), 256, 0, stream>>>(sa_out_w, wsao, Dn * Dn);
    conv_bf16<<<dim3((3 * Dn * Dn + 255) / 256), 256, 0, stream>>>(ca_in_w, wcain, 3 * Dn * Dn);
    conv_bf16<<<dim3((Dn * Dn + 255) / 256), 256, 0, stream>>>(ca_out_w, wcao, Dn * Dn);
    conv_bf16<<<dim3((Fn * Dn + 255) / 256), 256, 0, stream>>>(lin1_w, wlin1, Fn * Dn);
    conv_bf16<<<dim3((Dn * Fn + 255) / 256), 256, 0, stream>>>(lin2_w, wlin2, Dn * Fn);
    conv_bf16<<<dim3((Ln * HDn * HDn + 255) / 256), 256, 0, stream>>>(sa_rel, wrel, Ln * HDn * HDn);

    // ---- self-attention ----
    // q/k: (B,H,T,HD) bf16 ; v: (B,H,HD,T) bf16
    gemm(xb, wsaq, sa_q_b, qb, (int)BT, Dn, Dn, Dn, Dn, 0, 0, 0, 0, 0, 0, 0, 1, 1, 1.0f, 2, 0, Tn);
    gemm(xb, wsak, sa_k_b, kb, (int)BT, Dn, Dn, Dn, Dn, 0, 0, 0, 0, 0, 0, 0, 1, 1, 1.0f, 2, 0, Tn);
    gemm(xb, wsav, sa_v_b, vtb, (int)BT, Dn, Dn, Dn, Dn, 0, 0, 0, 0, 0, 0, 0, 1, 1, 1.0f, 3, 0, Tn);
    // uR[b,h,l] = q[b,h] @ R_l^T  (batched over B*H*L)
    gemm(qb, wrel, nullptr, ur, Tn, HDn, HDn, HDn, HDn, HDn,
         (long)Tn * HDn, 0, 0, (long)HDn * HDn, (long)Ln * Tn * HDn, (long)Tn * HDn,
         Ln, Bn * Hn * Ln, 1.0f, 1, 0, 0);
    // scores + edge-mask combine + scale + pad mask
    relscores<<<dim3(Tn / 64, Tn / 64, Bn), 256, 0, stream>>>(ur, kb, em, pad, sc);
    softmax_rows<<<dim3((Bn * Hn * Tn * 64 + 255) / 256), 256, 0, stream>>>(sc, Bn * Hn * Tn, Tn);
    // O = P @ V  (P bf16 aliased over score rows, lda = 2T ushorts)
    gemm((const unsigned short*)sc, vtb, nullptr, ob, Tn, HDn, Tn, 2 * Tn, Tn, Dn,
         (long)Hn * Tn * Tn * 2, (long)Tn * Tn * 2, (long)Hn * HDn * Tn, (long)HDn * Tn,
         (long)Tn * Dn, 64, Hn, Bn * Hn, 1.0f, 1, 0, 0);
    gemm(ob, wsao, sa_out_b, t2f, (int)BT, Dn, Dn, Dn, Dn, Dn, 0, 0, 0, 0, 0, 0, 1, 1, 1.0f, 0, 0, 0);
    ln_kernel<<<dim3((int)BT), 256, 0, stream>>>(tgt, 1, t2f, ln1_s, ln1_b, x1f, 0, x1b);

    // ---- cross-attention ----
    gemm(x1b, wcain, ca_in_b, qb, (int)BT, Dn, Dn, Dn, Dn, 0, 0, 0, 0, 0, 0, 0, 1, 1, 1.0f, 2, 0, Tn);
    gemm(mb, wcain + (size_t)Dn * Dn, ca_in_b + Dn, kb, (int)BT, Dn, Dn, Dn, Dn, 0,
         0, 0, 0, 0, 0, 0, 1, 1, 1.0f, 2, 0, Sn);
    gemm(mb, wcain + (size_t)2 * Dn * Dn, ca_in_b + 2 * Dn, vtb, (int)BT, Dn, Dn, Dn, Dn, 0,
         0, 0, 0, 0, 0, 0, 1, 1, 1.0f, 3, 0, Sn);
    // cs = scale * cq @ ck^T  (batched over B*H)
    gemm(qb, kb, nullptr, sc, Tn, Sn, HDn, HDn, HDn, Sn,
         (long)Tn * HDn, 0, (long)Sn * HDn, 0, (long)Tn * Sn, 0,
         1, Bn * Hn, SCALE, 0, 0, 0);
    softmax_rows<<<dim3((Bn * Hn * Tn * 64 + 255) / 256), 256, 0, stream>>>(sc, Bn * Hn * Tn, Sn);
    gemm((const unsigned short*)sc, vtb, nullptr, ob, Tn, HDn, Sn, 2 * Sn, Sn, Dn,
         (long)Hn * Tn * Sn * 2, (long)Tn * Sn * 2, (long)Hn * HDn * Sn, (long)HDn * Sn,
         (long)Tn * Dn, 64, Hn, Bn * Hn, 1.0f, 1, 0, 0);
    gemm(ob, wcao, ca_out_b, t2f, (int)BT, Dn, Dn, Dn, Dn, Dn, 0, 0, 0, 0, 0, 0, 1, 1, 1.0f, 0, 0, 0);
    ln_kernel<<<dim3((int)BT), 256, 0, stream>>>(x1f, 0, t2f, ln2_s, ln2_b, x2f, 0, x2b);

    // ---- FFN ----
    gemm(x2b, wlin1, lin1_b, hid, (int)BT, Fn, Dn, Dn, Dn, Fn, 0, 0, 0, 0, 0, 0, 1, 1, 1.0f, 1, 1, 0);
    gemm(hid, wlin2, lin2_b, t2f, (int)BT, Dn, Fn, Fn, Fn, Dn, 0, 0, 0, 0, 0, 0, 1, 1, 1.0f, 0, 0, 0);
    ln_kernel<<<dim3((int)BT), 256, 0, stream>>>(x2f, 0, t2f, ln3_s, ln3_b, (float*)d_out, 1, nullptr);
}